// Round 3
// baseline (3113.104 us; speedup 1.0000x reference)
//
#include <hip/hip_runtime.h>

#define BS 4096
#define NV 778
#define NJ 16
#define NC 45

__global__ __launch_bounds__(256) void mano_kernel(
    const float* __restrict__ root_rot,   // (BS,3,3)
    const float* __restrict__ pose,       // (BS,45)
    const float* __restrict__ shape,      // (BS,10)
    const float* __restrict__ trans,      // (BS,3)
    const float* __restrict__ hc,         // (45,45)
    const float* __restrict__ hmean,      // (45)
    const float* __restrict__ shapedirs,  // (NV,3,10)
    const float* __restrict__ posedirs,   // (NV,3,135)
    const float* __restrict__ v_template, // (NV,3)
    const float* __restrict__ JR,         // (NJ,NV)
    const float* __restrict__ weights,    // (NV,NJ)
    float* __restrict__ out)              // v_out (BS,NV,3) ++ j_out (BS,21,3)
{
    const int b = blockIdx.x;
    const int t = threadIdx.x;
    const int lane = t & 63;
    const int wave = t >> 6;

    __shared__ float s_pose[NC];
    __shared__ float s_shape[10];
    __shared__ float s_axis[NC];
    __shared__ float s_rot[135];   // 15 x 3x3
    __shared__ float s_pf[135];    // rot - I
    __shared__ float s_jt[NJ * 3]; // j_tpose
    __shared__ float s_A[NJ * 12]; // local [R|t] per joint (3 rows x 4)
    __shared__ float s_SE3[NJ * 12];
    __shared__ float s_red[4][48];
    __shared__ float s_jl[NJ * 3];
    __shared__ float s_tips[5 * 3];
    __shared__ float s_trans[3];

    // ---- stage small per-batch inputs ----
    if (t < NC) s_pose[t] = pose[b * NC + t];
    if (t >= 64 && t < 74) s_shape[t - 64] = shape[b * 10 + (t - 64)];
    if (t >= 128 && t < 131) s_trans[t - 128] = trans[b * 3 + (t - 128)];
    __syncthreads();

    // ---- axis = pose @ hands_components + hands_mean ----
    if (t < NC) {
        float acc = hmean[t];
        #pragma unroll 5
        for (int i = 0; i < NC; ++i) acc += s_pose[i] * hc[i * NC + t];
        s_axis[t] = acc;
    }
    __syncthreads();

    // ---- Rodrigues for 15 joints ----
    if (t < 15) {
        float ax = s_axis[t * 3 + 0], ay = s_axis[t * 3 + 1], az = s_axis[t * 3 + 2];
        float angle = sqrtf(ax * ax + ay * ay + az * az + 1e-12f);
        float inv = 1.0f / angle;
        float ux = ax * inv, uy = ay * inv, uz = az * inv;
        float c = cosf(angle), s = sinf(angle), ic = 1.0f - c;
        float R[9];
        R[0] = c + ic * ux * ux;      R[1] = -s * uz + ic * ux * uy; R[2] = s * uy + ic * ux * uz;
        R[3] = s * uz + ic * ux * uy; R[4] = c + ic * uy * uy;       R[5] = -s * ux + ic * uy * uz;
        R[6] = -s * uy + ic * ux * uz;R[7] = s * ux + ic * uy * uz;  R[8] = c + ic * uz * uz;
        #pragma unroll
        for (int k = 0; k < 9; ++k) {
            s_rot[t * 9 + k] = R[k];
            s_pf[t * 9 + k] = R[k] - ((k == 0 || k == 4 || k == 8) ? 1.0f : 0.0f);
        }
    }
    __syncthreads();

    // ---- pass 1: j_tpose = JR @ (v_template + shapedirs@shape) ----
    float jt[48];
    #pragma unroll
    for (int k = 0; k < 48; ++k) jt[k] = 0.0f;
    for (int v = t; v < NV; v += 256) {
        float vs[3];
        #pragma unroll
        for (int d = 0; d < 3; ++d) {
            float acc = v_template[v * 3 + d];
            const float* sd = shapedirs + v * 30 + d * 10;
            #pragma unroll
            for (int s2 = 0; s2 < 10; ++s2) acc += sd[s2] * s_shape[s2];
            vs[d] = acc;
        }
        #pragma unroll
        for (int j = 0; j < NJ; ++j) {
            float jr = JR[j * NV + v];
            jt[j * 3 + 0] += jr * vs[0];
            jt[j * 3 + 1] += jr * vs[1];
            jt[j * 3 + 2] += jr * vs[2];
        }
    }
    #pragma unroll
    for (int k = 0; k < 48; ++k) {
        float v = jt[k];
        #pragma unroll
        for (int off = 32; off > 0; off >>= 1) v += __shfl_down(v, off, 64);
        jt[k] = v;
    }
    if (lane == 0) {
        #pragma unroll
        for (int k = 0; k < 48; ++k) s_red[wave][k] = jt[k];
    }
    __syncthreads();
    if (t < 48) s_jt[t] = s_red[0][t] + s_red[1][t] + s_red[2][t] + s_red[3][t];
    __syncthreads();

    // ---- local SE3 pieces: A[i] = [R_i | j_i - R_i j_i] ----
    if (t < NJ) {
        float R[9];
        if (t == 0) {
            #pragma unroll
            for (int k = 0; k < 9; ++k) R[k] = root_rot[b * 9 + k];
        } else {
            #pragma unroll
            for (int k = 0; k < 9; ++k) R[k] = s_rot[(t - 1) * 9 + k];
        }
        float jx = s_jt[t * 3 + 0], jy = s_jt[t * 3 + 1], jz = s_jt[t * 3 + 2];
        #pragma unroll
        for (int r = 0; r < 3; ++r) {
            float jr = (r == 0) ? jx : ((r == 1) ? jy : jz);
            float ti = jr - (R[r * 3 + 0] * jx + R[r * 3 + 1] * jy + R[r * 3 + 2] * jz);
            s_A[t * 12 + r * 4 + 0] = R[r * 3 + 0];
            s_A[t * 12 + r * 4 + 1] = R[r * 3 + 1];
            s_A[t * 12 + r * 4 + 2] = R[r * 3 + 2];
            s_A[t * 12 + r * 4 + 3] = ti;
        }
    }
    __syncthreads();

    // ---- compose kinematic chains (5 independent chains of depth 3) ----
    if (t == 5) {
        #pragma unroll
        for (int k = 0; k < 12; ++k) s_SE3[k] = s_A[k];
    }
    if (t < 5) {
        float P[12];
        #pragma unroll
        for (int k = 0; k < 12; ++k) P[k] = s_A[k];  // root transform
        for (int step = 0; step < 3; ++step) {
            int i = t * 3 + 1 + step;
            float M[12];
            #pragma unroll
            for (int r = 0; r < 3; ++r) {
                #pragma unroll
                for (int c = 0; c < 3; ++c) {
                    M[r * 4 + c] = P[r * 4 + 0] * s_A[i * 12 + 0 * 4 + c]
                                 + P[r * 4 + 1] * s_A[i * 12 + 1 * 4 + c]
                                 + P[r * 4 + 2] * s_A[i * 12 + 2 * 4 + c];
                }
                M[r * 4 + 3] = P[r * 4 + 0] * s_A[i * 12 + 3]
                             + P[r * 4 + 1] * s_A[i * 12 + 7]
                             + P[r * 4 + 2] * s_A[i * 12 + 11]
                             + P[r * 4 + 3];
            }
            #pragma unroll
            for (int k = 0; k < 12; ++k) { s_SE3[i * 12 + k] = M[k]; P[k] = M[k]; }
        }
    }
    __syncthreads();

    // ---- posed joints (pre-reorder): jl[i] = SE3[parent] * j_tpose[i] ----
    if (t < NJ) {
        if (t == 0) {
            s_jl[0] = s_jt[0]; s_jl[1] = s_jt[1]; s_jl[2] = s_jt[2];
        } else {
            const int PAR[NJ] = {-1, 0, 1, 2, 0, 4, 5, 0, 7, 8, 0, 10, 11, 0, 13, 14};
            int p = PAR[t];
            float jx = s_jt[t * 3 + 0], jy = s_jt[t * 3 + 1], jz = s_jt[t * 3 + 2];
            #pragma unroll
            for (int r = 0; r < 3; ++r) {
                s_jl[t * 3 + r] = s_SE3[p * 12 + r * 4 + 0] * jx
                                + s_SE3[p * 12 + r * 4 + 1] * jy
                                + s_SE3[p * 12 + r * 4 + 2] * jz
                                + s_SE3[p * 12 + r * 4 + 3];
            }
        }
    }
    __syncthreads();

    // ---- pass 2: per-vertex blendshapes + LBS + final write ----
    const float cx = s_jt[0], cy = s_jt[1], cz = s_jt[2];  // center = j_tpose[0]
    const float tx = s_trans[0], ty = s_trans[1], tz = s_trans[2];
    for (int v = t; v < NV; v += 256) {
        float vt3[3];
        #pragma unroll
        for (int d = 0; d < 3; ++d) {
            float acc = v_template[v * 3 + d];
            const float* sd = shapedirs + v * 30 + d * 10;
            #pragma unroll
            for (int s2 = 0; s2 < 10; ++s2) acc += sd[s2] * s_shape[s2];
            const float* pd = posedirs + v * 405 + d * 135;
            float pacc = 0.0f;
            for (int p = 0; p < 135; ++p) pacc += pd[p] * s_pf[p];
            vt3[d] = acc + pacc;
        }
        float M[12];
        #pragma unroll
        for (int k = 0; k < 12; ++k) M[k] = 0.0f;
        #pragma unroll 4
        for (int j = 0; j < NJ; ++j) {
            float w = weights[v * NJ + j];
            #pragma unroll
            for (int k = 0; k < 12; ++k) M[k] += w * s_SE3[j * 12 + k];
        }
        float ox = M[0] * vt3[0] + M[1] * vt3[1] + M[2]  * vt3[2] + M[3]  - cx + tx;
        float oy = M[4] * vt3[0] + M[5] * vt3[1] + M[6]  * vt3[2] + M[7]  - cy + ty;
        float oz = M[8] * vt3[0] + M[9] * vt3[1] + M[10] * vt3[2] + M[11] - cz + tz;
        size_t o = (size_t)b * (NV * 3) + (size_t)v * 3;
        out[o + 0] = ox;
        out[o + 1] = oy;
        out[o + 2] = oz;
        int tip = (v == 745) ? 0 : (v == 333) ? 1 : (v == 444) ? 2 : (v == 555) ? 3 : (v == 672) ? 4 : -1;
        if (tip >= 0) {
            s_tips[tip * 3 + 0] = ox; s_tips[tip * 3 + 1] = oy; s_tips[tip * 3 + 2] = oz;
        }
    }
    __syncthreads();

    // ---- j_out: reorder, recenter ----
    if (t < 21) {
        const int NO[21] = {0, 13, 14, 15, 16, 1, 2, 3, 17, 4, 5, 6, 18, 10, 11, 12, 19, 7, 8, 9, 20};
        int src = NO[t];
        float vx, vy, vz;
        if (src < 16) {
            vx = s_jl[src * 3 + 0] - cx + tx;
            vy = s_jl[src * 3 + 1] - cy + ty;
            vz = s_jl[src * 3 + 2] - cz + tz;
        } else {
            vx = s_tips[(src - 16) * 3 + 0];
            vy = s_tips[(src - 16) * 3 + 1];
            vz = s_tips[(src - 16) * 3 + 2];
        }
        size_t base = (size_t)BS * (NV * 3) + (size_t)b * 63 + (size_t)t * 3;
        out[base + 0] = vx;
        out[base + 1] = vy;
        out[base + 2] = vz;
    }
}

extern "C" void kernel_launch(void* const* d_in, const int* in_sizes, int n_in,
                              void* d_out, int out_size, void* d_ws, size_t ws_size,
                              hipStream_t stream) {
    (void)in_sizes; (void)n_in; (void)d_ws; (void)ws_size; (void)out_size;
    mano_kernel<<<dim3(BS), dim3(256), 0, stream>>>(
        (const float*)d_in[0], (const float*)d_in[1], (const float*)d_in[2],
        (const float*)d_in[3], (const float*)d_in[4], (const float*)d_in[5],
        (const float*)d_in[6], (const float*)d_in[7], (const float*)d_in[8],
        (const float*)d_in[9], (const float*)d_in[10],
        (float*)d_out);
}

// Round 5
// 402.948 us; speedup vs baseline: 7.7258x; 7.7258x over previous
//
#include <hip/hip_runtime.h>

#define BS 4096
#define NV 778
#define NJ 16
#define NC 45

// ws float offsets
#define WS_JRS   0                       // 480 floats: (JR@shapedirs)[j,d,s]
#define WS_JRVT  480                     // 48 floats:  (JR@v_template)[j,d]
#define WS_SE3   528                     // BS*192
#define WS_PFT   (528 + BS*192)          // 135*BS, layout [p][b]
#define WS_SHIFT (WS_PFT + 135*BS)       // BS*4, trans - center

// ---------------- kernel A: batch-independent precompute ----------------
__global__ __launch_bounds__(64) void mano_pre(
    const float* __restrict__ shapedirs, const float* __restrict__ v_template,
    const float* __restrict__ JR, float* __restrict__ ws)
{
    int o = blockIdx.x;          // 0..527
    int lane = threadIdx.x;
    float acc = 0.0f;
    if (o < 480) {
        int j = o / 30, rem = o % 30;
        for (int v = lane; v < NV; v += 64)
            acc += JR[j * NV + v] * shapedirs[v * 30 + rem];
    } else {
        int o2 = o - 480;
        int j = o2 / 3, d = o2 % 3;
        for (int v = lane; v < NV; v += 64)
            acc += JR[j * NV + v] * v_template[v * 3 + d];
    }
    #pragma unroll
    for (int off = 32; off > 0; off >>= 1) acc += __shfl_down(acc, off, 64);
    if (lane == 0) ws[(o < 480) ? (WS_JRS + o) : (WS_JRVT + (o - 480))] = acc;
}

// ---------------- kernel B: per-batch prep (1 wave / batch) ----------------
__global__ __launch_bounds__(64) void mano_batch(
    const float* __restrict__ root_rot, const float* __restrict__ pose,
    const float* __restrict__ shape, const float* __restrict__ trans,
    const float* __restrict__ hc, const float* __restrict__ hmean,
    float* __restrict__ ws, float* __restrict__ out)
{
    const int b = blockIdx.x;
    const int t = threadIdx.x;

    __shared__ float s_pose[NC], s_shape[10], s_axis[NC];
    __shared__ float s_rot[135], s_pf[135];
    __shared__ float s_jt[48], s_A[192], s_SE3[192], s_jl[48], s_shift[3];

    if (t < NC) s_pose[t] = pose[b * NC + t];
    if (t < 10) s_shape[t] = shape[b * 10 + t];
    __syncthreads();

    if (t < NC) {
        float a = hmean[t];
        for (int i = 0; i < NC; ++i) a += s_pose[i] * hc[i * NC + t];
        s_axis[t] = a;
    }
    __syncthreads();

    if (t < 15) {   // Rodrigues
        float ax = s_axis[t*3+0], ay = s_axis[t*3+1], az = s_axis[t*3+2];
        float angle = sqrtf(ax*ax + ay*ay + az*az + 1e-12f);
        float inv = 1.0f / angle;
        float ux = ax*inv, uy = ay*inv, uz = az*inv;
        float c = cosf(angle), s = sinf(angle), ic = 1.0f - c;
        float R[9];
        R[0]=c+ic*ux*ux;       R[1]=-s*uz+ic*ux*uy;  R[2]= s*uy+ic*ux*uz;
        R[3]= s*uz+ic*ux*uy;   R[4]=c+ic*uy*uy;      R[5]=-s*ux+ic*uy*uz;
        R[6]=-s*uy+ic*ux*uz;   R[7]= s*ux+ic*uy*uz;  R[8]=c+ic*uz*uz;
        #pragma unroll
        for (int k = 0; k < 9; ++k) {
            s_rot[t*9+k] = R[k];
            s_pf[t*9+k]  = R[k] - ((k==0||k==4||k==8) ? 1.0f : 0.0f);
        }
    }
    if (t < 48) {   // j_tpose via JRS trick
        float a = ws[WS_JRVT + t];
        #pragma unroll
        for (int s2 = 0; s2 < 10; ++s2) a += ws[WS_JRS + t*10 + s2] * s_shape[s2];
        s_jt[t] = a;
    }
    __syncthreads();

    if (t < NJ) {   // local [R | j - R j]
        float R[9];
        if (t == 0) {
            #pragma unroll
            for (int k = 0; k < 9; ++k) R[k] = root_rot[b*9+k];
        } else {
            #pragma unroll
            for (int k = 0; k < 9; ++k) R[k] = s_rot[(t-1)*9+k];
        }
        float jx = s_jt[t*3+0], jy = s_jt[t*3+1], jz = s_jt[t*3+2];
        #pragma unroll
        for (int r = 0; r < 3; ++r) {
            float jr = (r==0)?jx:((r==1)?jy:jz);
            float ti = jr - (R[r*3+0]*jx + R[r*3+1]*jy + R[r*3+2]*jz);
            s_A[t*12+r*4+0]=R[r*3+0]; s_A[t*12+r*4+1]=R[r*3+1];
            s_A[t*12+r*4+2]=R[r*3+2]; s_A[t*12+r*4+3]=ti;
        }
    }
    __syncthreads();

    if (t == 5) {
        #pragma unroll
        for (int k = 0; k < 12; ++k) s_SE3[k] = s_A[k];
    }
    if (t < 5) {    // 5 chains of depth 3
        float P[12];
        #pragma unroll
        for (int k = 0; k < 12; ++k) P[k] = s_A[k];
        for (int step = 0; step < 3; ++step) {
            int i = t*3 + 1 + step;
            float M[12];
            #pragma unroll
            for (int r = 0; r < 3; ++r) {
                #pragma unroll
                for (int c = 0; c < 3; ++c)
                    M[r*4+c] = P[r*4+0]*s_A[i*12+0*4+c] + P[r*4+1]*s_A[i*12+1*4+c]
                             + P[r*4+2]*s_A[i*12+2*4+c];
                M[r*4+3] = P[r*4+0]*s_A[i*12+3] + P[r*4+1]*s_A[i*12+7]
                         + P[r*4+2]*s_A[i*12+11] + P[r*4+3];
            }
            #pragma unroll
            for (int k = 0; k < 12; ++k) { s_SE3[i*12+k] = M[k]; P[k] = M[k]; }
        }
    }
    __syncthreads();

    if (t < NJ) {   // posed joints
        if (t == 0) { s_jl[0]=s_jt[0]; s_jl[1]=s_jt[1]; s_jl[2]=s_jt[2]; }
        else {
            const int PAR[NJ] = {-1,0,1,2,0,4,5,0,7,8,0,10,11,0,13,14};
            int p = PAR[t];
            float jx = s_jt[t*3+0], jy = s_jt[t*3+1], jz = s_jt[t*3+2];
            #pragma unroll
            for (int r = 0; r < 3; ++r)
                s_jl[t*3+r] = s_SE3[p*12+r*4+0]*jx + s_SE3[p*12+r*4+1]*jy
                            + s_SE3[p*12+r*4+2]*jz + s_SE3[p*12+r*4+3];
        }
    }
    if (t < 3) s_shift[t] = trans[b*3+t] - s_jt[t];
    __syncthreads();

    // ---- stores ----
    for (int k = t; k < 135; k += 64) ws[WS_PFT + k*BS + b] = s_pf[k];
    for (int k = t; k < 192; k += 64) ws[WS_SE3 + b*192 + k] = s_SE3[k];
    if (t < 3) ws[WS_SHIFT + b*4 + t] = s_shift[t];
    if (t < 21) {
        const int NO[21] = {0,13,14,15,16,1,2,3,17,4,5,6,18,10,11,12,19,7,8,9,20};
        int src = NO[t];
        if (src < 16) {
            size_t jb = (size_t)BS*2334 + (size_t)b*63 + (size_t)t*3;
            out[jb+0] = s_jl[src*3+0] + s_shift[0];
            out[jb+1] = s_jl[src*3+1] + s_shift[1];
            out[jb+2] = s_jl[src*3+2] + s_shift[2];
        }
    }
}

// ---------------- kernel C: vertices (64-batch x 64-vertex tiles) ----------------
__global__ __launch_bounds__(256) void mano_verts(
    const float* __restrict__ posedirs, const float* __restrict__ shapedirs,
    const float* __restrict__ v_template, const float* __restrict__ shape,
    const float* __restrict__ weights, const float* __restrict__ ws,
    float* __restrict__ out)
{
    const int btile = blockIdx.x;   // 0..63
    const int vstrip = blockIdx.y;  // 0..12
    const int t = threadIdx.x;
    const int lane = t & 63;
    const int w = __builtin_amdgcn_readfirstlane(t >> 6);
    const int v0 = vstrip * 64;
    const int bg0 = btile * 64;

    __shared__ float s_vx[64*65];
    __shared__ float s_vy[64*65];
    __shared__ float s_vz[64*65];
    __shared__ float s_w[64*17];

    // stage weights tile (padded 17 -> conflict-free)
    for (int idx = t; idx < 64*16; idx += 256) {
        int vl = idx >> 4, j = idx & 15;
        int vg = v0 + vl;
        s_w[vl*17+j] = (vg < NV) ? weights[vg*16+j] : 0.0f;
    }

    // ---- phase 1: lane = batch, 16 vertices per wave ----
    const float* pfT = ws + WS_PFT;
    const int bg = bg0 + lane;
    float shp[10];
    #pragma unroll
    for (int s = 0; s < 10; ++s) shp[s] = shape[bg*10+s];

    float acc[16][3];
    #pragma unroll
    for (int vi = 0; vi < 16; ++vi) {
        int vg = v0 + w*16 + vi; if (vg > NV-1) vg = NV-1;
        #pragma unroll
        for (int d = 0; d < 3; ++d) {
            float a = v_template[vg*3+d];
            #pragma unroll
            for (int s = 0; s < 10; ++s) a += shapedirs[vg*30+d*10+s] * shp[s];
            acc[vi][d] = a;
        }
    }
    for (int c = 0; c < 135; c += 27) {     // 5 chunks
        float pfr[27];
        #pragma unroll
        for (int q = 0; q < 27; ++q) pfr[q] = pfT[(c+q)*BS + bg];
        #pragma unroll
        for (int vi = 0; vi < 16; ++vi) {
            int vg = v0 + w*16 + vi; if (vg > NV-1) vg = NV-1;
            const float* pd = posedirs + vg*405 + c;
            #pragma unroll
            for (int d = 0; d < 3; ++d) {
                float a = acc[vi][d];
                #pragma unroll
                for (int q = 0; q < 27; ++q) a += pd[d*135+q] * pfr[q];
                acc[vi][d] = a;
            }
        }
    }
    #pragma unroll
    for (int vi = 0; vi < 16; ++vi) {
        int vl = w*16 + vi;
        s_vx[vl*65+lane] = acc[vi][0];
        s_vy[vl*65+lane] = acc[vi][1];
        s_vz[vl*65+lane] = acc[vi][2];
    }
    __syncthreads();

    // ---- phase 2: lane = vertex, 16 batches per wave ----
    const float* se3w = ws + WS_SE3;
    const float* shiftw = ws + WS_SHIFT;
    const int vg = v0 + lane;
    const bool vok = (vg < NV);
    float wj[16];
    #pragma unroll
    for (int j = 0; j < 16; ++j) wj[j] = s_w[lane*17+j];

    int slot = -1;
    if (vg == 745) slot = 4; else if (vg == 333) slot = 8; else if (vg == 444) slot = 12;
    else if (vg == 555) slot = 16; else if (vg == 672) slot = 20;

    for (int i = 0; i < 16; ++i) {
        const int bl = w*16 + i;
        const int b = bg0 + bl;             // wave-uniform
        const float* S = se3w + (size_t)b*192;
        float M[12];
        #pragma unroll
        for (int k = 0; k < 12; ++k) M[k] = 0.0f;
        #pragma unroll
        for (int j = 0; j < 16; ++j) {
            float wv = wj[j];
            #pragma unroll
            for (int k = 0; k < 12; ++k) M[k] += wv * S[j*12+k];
        }
        float vx = s_vx[lane*65+bl], vy = s_vy[lane*65+bl], vz = s_vz[lane*65+bl];
        float sx = shiftw[b*4+0], sy = shiftw[b*4+1], sz = shiftw[b*4+2];
        float ox = M[0]*vx + M[1]*vy + M[2] *vz + M[3]  + sx;
        float oy = M[4]*vx + M[5]*vy + M[6] *vz + M[7]  + sy;
        float oz = M[8]*vx + M[9]*vy + M[10]*vz + M[11] + sz;
        if (vok) {
            size_t o = (size_t)b*2334 + (size_t)vg*3;
            out[o+0] = ox; out[o+1] = oy; out[o+2] = oz;
            if (slot >= 0) {
                size_t jb = (size_t)BS*2334 + (size_t)b*63 + (size_t)slot*3;
                out[jb+0] = ox; out[jb+1] = oy; out[jb+2] = oz;
            }
        }
    }
}

extern "C" void kernel_launch(void* const* d_in, const int* in_sizes, int n_in,
                              void* d_out, int out_size, void* d_ws, size_t ws_size,
                              hipStream_t stream) {
    (void)in_sizes; (void)n_in; (void)ws_size; (void)out_size;
    const float* root_rot   = (const float*)d_in[0];
    const float* pose       = (const float*)d_in[1];
    const float* shape      = (const float*)d_in[2];
    const float* trans      = (const float*)d_in[3];
    const float* hc         = (const float*)d_in[4];
    const float* hmean      = (const float*)d_in[5];
    const float* shapedirs  = (const float*)d_in[6];
    const float* posedirs   = (const float*)d_in[7];
    const float* v_template = (const float*)d_in[8];
    const float* JR         = (const float*)d_in[9];
    const float* weights    = (const float*)d_in[10];
    float* ws  = (float*)d_ws;
    float* out = (float*)d_out;

    mano_pre<<<dim3(528), dim3(64), 0, stream>>>(shapedirs, v_template, JR, ws);
    mano_batch<<<dim3(BS), dim3(64), 0, stream>>>(root_rot, pose, shape, trans,
                                                  hc, hmean, ws, out);
    mano_verts<<<dim3(64, 13), dim3(256), 0, stream>>>(posedirs, shapedirs, v_template,
                                                       shape, weights, ws, out);
}

// Round 6
// 268.480 us; speedup vs baseline: 11.5953x; 1.5008x over previous
//
#include <hip/hip_runtime.h>

#define BS 4096
#define NV 778
#define NJ 16
#define NC 45

// ws float offsets
#define WS_JRS   0                       // 480 floats: (JR@shapedirs)[j,d,s]
#define WS_JRVT  480                     // 48 floats:  (JR@v_template)[j,d]
#define WS_SE3   528                     // BS*192
#define WS_PFT   (528 + BS*192)          // 135*BS, layout [p][b]
#define WS_SHIFT (WS_PFT + 135*BS)       // BS*4, trans - center

// ---------------- kernel A: batch-independent precompute ----------------
__global__ __launch_bounds__(64) void mano_pre(
    const float* __restrict__ shapedirs, const float* __restrict__ v_template,
    const float* __restrict__ JR, float* __restrict__ ws)
{
    int o = blockIdx.x;          // 0..527
    int lane = threadIdx.x;
    float acc = 0.0f;
    if (o < 480) {
        int j = o / 30, rem = o % 30;
        for (int v = lane; v < NV; v += 64)
            acc += JR[j * NV + v] * shapedirs[v * 30 + rem];
    } else {
        int o2 = o - 480;
        int j = o2 / 3, d = o2 % 3;
        for (int v = lane; v < NV; v += 64)
            acc += JR[j * NV + v] * v_template[v * 3 + d];
    }
    #pragma unroll
    for (int off = 32; off > 0; off >>= 1) acc += __shfl_down(acc, off, 64);
    if (lane == 0) ws[(o < 480) ? (WS_JRS + o) : (WS_JRVT + (o - 480))] = acc;
}

// ---------------- kernel B: per-batch prep (1 wave / batch) ----------------
__global__ __launch_bounds__(64) void mano_batch(
    const float* __restrict__ root_rot, const float* __restrict__ pose,
    const float* __restrict__ shape, const float* __restrict__ trans,
    const float* __restrict__ hc, const float* __restrict__ hmean,
    float* __restrict__ ws, float* __restrict__ out)
{
    const int b = blockIdx.x;
    const int t = threadIdx.x;

    __shared__ float s_pose[NC], s_shape[10], s_axis[NC];
    __shared__ float s_rot[135], s_pf[135];
    __shared__ float s_jt[48], s_A[192], s_SE3[192], s_jl[48], s_shift[3];

    if (t < NC) s_pose[t] = pose[b * NC + t];
    if (t < 10) s_shape[t] = shape[b * 10 + t];
    __syncthreads();

    if (t < NC) {
        float a = hmean[t];
        for (int i = 0; i < NC; ++i) a += s_pose[i] * hc[i * NC + t];
        s_axis[t] = a;
    }
    __syncthreads();

    if (t < 15) {   // Rodrigues
        float ax = s_axis[t*3+0], ay = s_axis[t*3+1], az = s_axis[t*3+2];
        float angle = sqrtf(ax*ax + ay*ay + az*az + 1e-12f);
        float inv = 1.0f / angle;
        float ux = ax*inv, uy = ay*inv, uz = az*inv;
        float c = cosf(angle), s = sinf(angle), ic = 1.0f - c;
        float R[9];
        R[0]=c+ic*ux*ux;       R[1]=-s*uz+ic*ux*uy;  R[2]= s*uy+ic*ux*uz;
        R[3]= s*uz+ic*ux*uy;   R[4]=c+ic*uy*uy;      R[5]=-s*ux+ic*uy*uz;
        R[6]=-s*uy+ic*ux*uz;   R[7]= s*ux+ic*uy*uz;  R[8]=c+ic*uz*uz;
        #pragma unroll
        for (int k = 0; k < 9; ++k) {
            s_rot[t*9+k] = R[k];
            s_pf[t*9+k]  = R[k] - ((k==0||k==4||k==8) ? 1.0f : 0.0f);
        }
    }
    if (t < 48) {   // j_tpose via (JR@shapedirs) trick
        float a = ws[WS_JRVT + t];
        #pragma unroll
        for (int s2 = 0; s2 < 10; ++s2) a += ws[WS_JRS + t*10 + s2] * s_shape[s2];
        s_jt[t] = a;
    }
    __syncthreads();

    if (t < NJ) {   // local [R | j - R j]
        float R[9];
        if (t == 0) {
            #pragma unroll
            for (int k = 0; k < 9; ++k) R[k] = root_rot[b*9+k];
        } else {
            #pragma unroll
            for (int k = 0; k < 9; ++k) R[k] = s_rot[(t-1)*9+k];
        }
        float jx = s_jt[t*3+0], jy = s_jt[t*3+1], jz = s_jt[t*3+2];
        #pragma unroll
        for (int r = 0; r < 3; ++r) {
            float jr = (r==0)?jx:((r==1)?jy:jz);
            float ti = jr - (R[r*3+0]*jx + R[r*3+1]*jy + R[r*3+2]*jz);
            s_A[t*12+r*4+0]=R[r*3+0]; s_A[t*12+r*4+1]=R[r*3+1];
            s_A[t*12+r*4+2]=R[r*3+2]; s_A[t*12+r*4+3]=ti;
        }
    }
    __syncthreads();

    if (t == 5) {
        #pragma unroll
        for (int k = 0; k < 12; ++k) s_SE3[k] = s_A[k];
    }
    if (t < 5) {    // 5 chains of depth 3
        float P[12];
        #pragma unroll
        for (int k = 0; k < 12; ++k) P[k] = s_A[k];
        for (int step = 0; step < 3; ++step) {
            int i = t*3 + 1 + step;
            float M[12];
            #pragma unroll
            for (int r = 0; r < 3; ++r) {
                #pragma unroll
                for (int c = 0; c < 3; ++c)
                    M[r*4+c] = P[r*4+0]*s_A[i*12+0*4+c] + P[r*4+1]*s_A[i*12+1*4+c]
                             + P[r*4+2]*s_A[i*12+2*4+c];
                M[r*4+3] = P[r*4+0]*s_A[i*12+3] + P[r*4+1]*s_A[i*12+7]
                         + P[r*4+2]*s_A[i*12+11] + P[r*4+3];
            }
            #pragma unroll
            for (int k = 0; k < 12; ++k) { s_SE3[i*12+k] = M[k]; P[k] = M[k]; }
        }
    }
    __syncthreads();

    if (t < NJ) {   // posed joints
        if (t == 0) { s_jl[0]=s_jt[0]; s_jl[1]=s_jt[1]; s_jl[2]=s_jt[2]; }
        else {
            const int PAR[NJ] = {-1,0,1,2,0,4,5,0,7,8,0,10,11,0,13,14};
            int p = PAR[t];
            float jx = s_jt[t*3+0], jy = s_jt[t*3+1], jz = s_jt[t*3+2];
            #pragma unroll
            for (int r = 0; r < 3; ++r)
                s_jl[t*3+r] = s_SE3[p*12+r*4+0]*jx + s_SE3[p*12+r*4+1]*jy
                            + s_SE3[p*12+r*4+2]*jz + s_SE3[p*12+r*4+3];
        }
    }
    if (t < 3) s_shift[t] = trans[b*3+t] - s_jt[t];
    __syncthreads();

    // ---- stores ----
    for (int k = t; k < 135; k += 64) ws[WS_PFT + k*BS + b] = s_pf[k];
    for (int k = t; k < 192; k += 64) ws[WS_SE3 + b*192 + k] = s_SE3[k];
    if (t < 4) ws[WS_SHIFT + b*4 + t] = (t < 3) ? s_shift[t] : 0.0f;
    if (t < 21) {
        const int NO[21] = {0,13,14,15,16,1,2,3,17,4,5,6,18,10,11,12,19,7,8,9,20};
        int src = NO[t];
        if (src < 16) {
            size_t jb = (size_t)BS*2334 + (size_t)b*63 + (size_t)t*3;
            out[jb+0] = s_jl[src*3+0] + s_shift[0];
            out[jb+1] = s_jl[src*3+1] + s_shift[1];
            out[jb+2] = s_jl[src*3+2] + s_shift[2];
        }
    }
}

// ---------------- kernel C: GEMM (K=146) + fused LBS ----------------
// Block: 64 batches x 16 vertices (48 GEMM cols). Thread: 4 batches x 1 vertex.
__global__ __launch_bounds__(256) void mano_verts(
    const float* __restrict__ posedirs, const float* __restrict__ shapedirs,
    const float* __restrict__ v_template, const float* __restrict__ shape,
    const float* __restrict__ weights, const float* __restrict__ ws,
    float* __restrict__ out)
{
    const int btile = blockIdx.x;   // 0..63
    const int vtile = blockIdx.y;   // 0..48
    const int t = threadIdx.x;
    const int b0 = btile * 64;
    const int v0 = vtile * 16;

    __shared__ union {
        struct { float As[148*64]; float Bs[48*148]; } g;  // GEMM staging
        float Ss[64*196];                                  // SE3 tile (epilogue)
    } u;
    __shared__ float s_w[16*17];    // weights tile, padded
    __shared__ float s_sh[64*4];    // shift tile

    // ---- stage weights + shift (persist across phases) ----
    {
        int vl = t >> 4, j = t & 15;
        int vg = v0 + vl; if (vg > NV-1) vg = NV-1;
        s_w[vl*17 + j] = weights[vg*16 + j];
    }
    s_sh[t] = ws[WS_SHIFT + b0*4 + t];   // 256 = 64*4 contiguous

    // ---- stage A: [k=148][b=64];  k<135 pf, 135..144 shape, 145 = 1, 146+ = 0 ----
    const float* pfT = ws + WS_PFT;
    for (int idx = t; idx < 148*64; idx += 256) {
        int k = idx >> 6, j = idx & 63;
        float v;
        if (k < 135)       v = pfT[k*BS + b0 + j];
        else if (k < 145)  v = shape[(b0 + j)*10 + (k - 135)];
        else if (k == 145) v = 1.0f;
        else               v = 0.0f;
        u.g.As[k*64 + j] = v;
    }
    // ---- stage B: [col=48][k=148] ----
    for (int idx = t; idx < 48*135; idx += 256) {
        int col = idx / 135, k = idx - col*135;
        int vg = v0 + col/3; if (vg > NV-1) vg = NV-1;
        int d = col % 3;
        u.g.Bs[col*148 + k] = posedirs[vg*405 + d*135 + k];
    }
    for (int idx = t; idx < 48*13; idx += 256) {
        int col = idx / 13, k2 = idx - col*13;
        int vg = v0 + col/3; if (vg > NV-1) vg = NV-1;
        int d = col % 3;
        float v;
        if (k2 < 10)       v = shapedirs[vg*30 + d*10 + k2];
        else if (k2 == 10) v = v_template[vg*3 + d];
        else               v = 0.0f;
        u.g.Bs[col*148 + 135 + k2] = v;
    }
    __syncthreads();

    // ---- GEMM main loop ----
    const int vi = t & 15, bq = t >> 4;
    float acc[4][3];
    #pragma unroll
    for (int i = 0; i < 4; ++i)
        #pragma unroll
        for (int c = 0; c < 3; ++c) acc[i][c] = 0.0f;

    for (int r = 0; r < 37; ++r) {
        const int kk = r * 4;
        float a_[4][4];   // a_[k'][ib]
        #pragma unroll
        for (int kq = 0; kq < 4; ++kq)
            *(float4*)&a_[kq][0] = *(const float4*)&u.g.As[(kk+kq)*64 + bq*4];
        float b_[3][4];   // b_[c][k']
        #pragma unroll
        for (int c = 0; c < 3; ++c)
            *(float4*)&b_[c][0] = *(const float4*)&u.g.Bs[(vi*3 + c)*148 + kk];
        #pragma unroll
        for (int ib = 0; ib < 4; ++ib)
            #pragma unroll
            for (int c = 0; c < 3; ++c)
                acc[ib][c] += a_[0][ib]*b_[c][0] + a_[1][ib]*b_[c][1]
                            + a_[2][ib]*b_[c][2] + a_[3][ib]*b_[c][3];
    }
    __syncthreads();

    // ---- stage SE3 tile into (reused) LDS: Ss[b][196] ----
    const float* se3w = ws + WS_SE3 + (size_t)b0*192;
    for (int idx = t; idx < 64*192; idx += 256) {
        int b = idx / 192, k = idx - b*192;
        u.Ss[b*196 + k] = se3w[idx];
    }
    __syncthreads();

    // ---- LBS epilogue ----
    float wj[16];
    #pragma unroll
    for (int j = 0; j < 16; ++j) wj[j] = s_w[vi*17 + j];
    const int vg = v0 + vi;
    const bool vok = (vg < NV);
    int slot = -1;
    if (vg == 745) slot = 4; else if (vg == 333) slot = 8; else if (vg == 444) slot = 12;
    else if (vg == 555) slot = 16; else if (vg == 672) slot = 20;

    #pragma unroll
    for (int ib = 0; ib < 4; ++ib) {
        const int bl = bq*4 + ib;
        const int bg = b0 + bl;
        const float* S = &u.Ss[bl*196];
        float M[12];
        #pragma unroll
        for (int k = 0; k < 12; ++k) M[k] = 0.0f;
        #pragma unroll
        for (int j = 0; j < 16; ++j) {
            float w = wj[j];
            float4 r0 = *(const float4*)&S[j*12 + 0];
            float4 r1 = *(const float4*)&S[j*12 + 4];
            float4 r2 = *(const float4*)&S[j*12 + 8];
            M[0] += w*r0.x; M[1] += w*r0.y; M[2]  += w*r0.z; M[3]  += w*r0.w;
            M[4] += w*r1.x; M[5] += w*r1.y; M[6]  += w*r1.z; M[7]  += w*r1.w;
            M[8] += w*r2.x; M[9] += w*r2.y; M[10] += w*r2.z; M[11] += w*r2.w;
        }
        float x = acc[ib][0], y = acc[ib][1], z = acc[ib][2];
        float ox = M[0]*x + M[1]*y + M[2] *z + M[3]  + s_sh[bl*4+0];
        float oy = M[4]*x + M[5]*y + M[6] *z + M[7]  + s_sh[bl*4+1];
        float oz = M[8]*x + M[9]*y + M[10]*z + M[11] + s_sh[bl*4+2];
        if (vok) {
            size_t o = (size_t)bg*2334 + (size_t)vg*3;
            out[o+0] = ox; out[o+1] = oy; out[o+2] = oz;
            if (slot >= 0) {
                size_t jb = (size_t)BS*2334 + (size_t)bg*63 + (size_t)slot*3;
                out[jb+0] = ox; out[jb+1] = oy; out[jb+2] = oz;
            }
        }
    }
}

extern "C" void kernel_launch(void* const* d_in, const int* in_sizes, int n_in,
                              void* d_out, int out_size, void* d_ws, size_t ws_size,
                              hipStream_t stream) {
    (void)in_sizes; (void)n_in; (void)ws_size; (void)out_size;
    const float* root_rot   = (const float*)d_in[0];
    const float* pose       = (const float*)d_in[1];
    const float* shape      = (const float*)d_in[2];
    const float* trans      = (const float*)d_in[3];
    const float* hc         = (const float*)d_in[4];
    const float* hmean      = (const float*)d_in[5];
    const float* shapedirs  = (const float*)d_in[6];
    const float* posedirs   = (const float*)d_in[7];
    const float* v_template = (const float*)d_in[8];
    const float* JR         = (const float*)d_in[9];
    const float* weights    = (const float*)d_in[10];
    float* ws  = (float*)d_ws;
    float* out = (float*)d_out;

    mano_pre<<<dim3(528), dim3(64), 0, stream>>>(shapedirs, v_template, JR, ws);
    mano_batch<<<dim3(BS), dim3(64), 0, stream>>>(root_rot, pose, shape, trans,
                                                  hc, hmean, ws, out);
    mano_verts<<<dim3(64, 49), dim3(256), 0, stream>>>(posedirs, shapedirs, v_template,
                                                       shape, weights, ws, out);
}